// Round 4
// baseline (52.747 us; speedup 1.0000x reference)
//
#include <hip/hip_runtime.h>
#include <math.h>

#define NGRAPH 128
#define NNODE  200
#define FIN    200
#define DIM    32
#define EPER   6400
#define ETOT   819200
#define KP1    100
#define KP2    50

// sW layout offsets (floats)
#define W1B_OFF  0
#define W2A_OFF  1024
#define W2B_OFF  2048
#define B1A_OFF  3072
#define B1B_OFF  3104
#define B2A_OFF  3136
#define B2B_OFF  3168
#define PW1_OFF  3200
#define PW2_OFF  3232
#define NRM1_OFF 3264
#define NRM2_OFF 3265
#define SW_SIZE  3280

// XOR chunk swizzle for [row][32]-float LDS tiles.
__device__ __forceinline__ int swz(int row, int chunk) {
  return (row << 5) + (((chunk ^ ((row >> 2) & 7))) << 2);
}

__device__ __forceinline__ void lds_spin(volatile int* f, int target) {
  while (*f != target) __builtin_amdgcn_s_sleep(2);
}

// [ROWS]x32 @ 32x32, 2 rows/thread (tid < ROWS*2).
// FUSE: A-operand = relu(A[p] + A2[p] + fb[chunk]) on the fly (GIN add+relu).
// SCORE: also emit pool score tanh(dot(h_row, pw)/nrm) via 4-lane shfl reduce.
template <int ROWS, bool RELU, bool BIAS, bool FUSE, bool SCORE>
__device__ __forceinline__ void mm2r(const float* __restrict__ A,
                                     const float* __restrict__ A2,
                                     const float* __restrict__ fb,
                                     const float* __restrict__ W,
                                     float* __restrict__ O,
                                     const float* __restrict__ bias,
                                     const float* __restrict__ pw,
                                     const float* __restrict__ nrmp,
                                     float* __restrict__ scoreOut, int tid) {
  if (tid < ROWS * 2) {
    const int rg = tid >> 2, cg = tid & 3;
    const int r0 = rg * 2, d0 = cg * 8;
    float acc[2][8];
#pragma unroll
    for (int r = 0; r < 2; ++r)
#pragma unroll
      for (int c = 0; c < 8; ++c) acc[r][c] = 0.f;
#pragma unroll
    for (int kc = 0; kc < 8; ++kc) {
      float4 av[2];
#pragma unroll
      for (int r = 0; r < 2; ++r) {
        const int p = swz(r0 + r, kc);
        float4 v = *(const float4*)&A[p];
        if (FUSE) {
          const float4 u = *(const float4*)&A2[p];
          const float4 b = *(const float4*)&fb[kc * 4];
          v.x = fmaxf(v.x + u.x + b.x, 0.f);
          v.y = fmaxf(v.y + u.y + b.y, 0.f);
          v.z = fmaxf(v.z + u.z + b.z, 0.f);
          v.w = fmaxf(v.w + u.w + b.w, 0.f);
        }
        av[r] = v;
      }
#pragma unroll
      for (int j = 0; j < 4; ++j) {
        const int k = kc * 4 + j;
        const float4 wa = *(const float4*)&W[k * 32 + d0];
        const float4 wb = *(const float4*)&W[k * 32 + d0 + 4];
#pragma unroll
        for (int r = 0; r < 2; ++r) {
          const float xs = (j == 0) ? av[r].x : (j == 1) ? av[r].y
                                  : (j == 2) ? av[r].z : av[r].w;
          acc[r][0] += xs * wa.x; acc[r][1] += xs * wa.y;
          acc[r][2] += xs * wa.z; acc[r][3] += xs * wa.w;
          acc[r][4] += xs * wb.x; acc[r][5] += xs * wb.y;
          acc[r][6] += xs * wb.z; acc[r][7] += xs * wb.w;
        }
      }
    }
    float dot[2] = {0.f, 0.f};
#pragma unroll
    for (int r = 0; r < 2; ++r) {
      float v[8];
#pragma unroll
      for (int c = 0; c < 8; ++c) {
        float t = acc[r][c];
        if (BIAS) t += bias[d0 + c];
        if (RELU) t = fmaxf(t, 0.f);
        v[c] = t;
      }
      if (SCORE) {
        float d = 0.f;
#pragma unroll
        for (int c = 0; c < 8; ++c) d += v[c] * pw[d0 + c];
        dot[r] = d;
      }
      float4 o0, o1;
      o0.x = v[0]; o0.y = v[1]; o0.z = v[2]; o0.w = v[3];
      o1.x = v[4]; o1.y = v[5]; o1.z = v[6]; o1.w = v[7];
      *(float4*)&O[swz(r0 + r, cg * 2)] = o0;
      *(float4*)&O[swz(r0 + r, cg * 2 + 1)] = o1;
    }
    if (SCORE) {
      dot[0] += __shfl_xor(dot[0], 1); dot[0] += __shfl_xor(dot[0], 2);
      dot[1] += __shfl_xor(dot[1], 1); dot[1] += __shfl_xor(dot[1], 2);
      if ((tid & 3) == 0) {
        const float nrm = *nrmp;
        scoreOut[r0] = tanhf(dot[0] / nrm);
        scoreOut[r0 + 1] = tanhf(dot[1] / nrm);
      }
    }
  }
}

// exclusive prefix over 256 counters (4-padded) by one full wave; lane 0..63
__device__ __forceinline__ void scan_counts(const int* __restrict__ cnt,
                                            int* __restrict__ start, int lane) {
  const int b = lane * 4;
  const int c0 = (cnt[b + 0] + 3) & ~3;
  const int c1 = (cnt[b + 1] + 3) & ~3;
  const int c2 = (cnt[b + 2] + 3) & ~3;
  const int c3 = (cnt[b + 3] + 3) & ~3;
  const int t01 = c0 + c1;
  const int t012 = t01 + c2;
  const int tot = t012 + c3;
  int run = tot;
#pragma unroll
  for (int off = 1; off < 64; off <<= 1) {
    const int t = __shfl_up(run, off);
    if (lane >= off) run += t;
  }
  const int e = run - tot;
  start[b + 0] = e;
  start[b + 1] = e + c0;
  start[b + 2] = e + t01;
  start[b + 3] = e + t012;
}

// 128 node-slots x 8 float4-parts
template <int NN>
__device__ __forceinline__ void aggregate(const float* __restrict__ sYv,
                                          float* __restrict__ sAgv,
                                          const int* __restrict__ sSrcv,
                                          const int* __restrict__ sStartv,
                                          const int* __restrict__ sCntv, int tid) {
  const int slot = tid >> 3, part = tid & 7;
#pragma unroll
  for (int p = 0; p < (NN + 127) / 128; ++p) {
    const int n = p * 128 + slot;
    if (n < NN) {
      const int jb = sStartv[n];
      const int je = jb + sCntv[n];
      float4 a0 = {0, 0, 0, 0}, a1 = {0, 0, 0, 0}, a2 = {0, 0, 0, 0}, a3 = {0, 0, 0, 0};
      int j = jb;
      for (; j + 4 <= je; j += 4) {
        const int4 ss = *(const int4*)&sSrcv[j];
        const float4 v0 = *(const float4*)&sYv[swz(ss.x, part)];
        const float4 v1 = *(const float4*)&sYv[swz(ss.y, part)];
        const float4 v2 = *(const float4*)&sYv[swz(ss.z, part)];
        const float4 v3 = *(const float4*)&sYv[swz(ss.w, part)];
        a0.x += v0.x; a0.y += v0.y; a0.z += v0.z; a0.w += v0.w;
        a1.x += v1.x; a1.y += v1.y; a1.z += v1.z; a1.w += v1.w;
        a2.x += v2.x; a2.y += v2.y; a2.z += v2.z; a2.w += v2.w;
        a3.x += v3.x; a3.y += v3.y; a3.z += v3.z; a3.w += v3.w;
      }
      for (; j < je; ++j) {
        const float4 v = *(const float4*)&sYv[swz(sSrcv[j], part)];
        a0.x += v.x; a0.y += v.y; a0.z += v.z; a0.w += v.w;
      }
      float4 o;
      o.x = (a0.x + a1.x) + (a2.x + a3.x);
      o.y = (a0.y + a1.y) + (a2.y + a3.y);
      o.z = (a0.z + a1.z) + (a2.z + a3.z);
      o.w = (a0.w + a1.w) + (a2.w + a3.w);
      *(float4*)&sAgv[swz(n, part)] = o;
    }
  }
}

// ============ single fused kernel: one block per graph ======
__global__ __launch_bounds__(1024, 1) void gin_fused(
    const float* __restrict__ x, const int* __restrict__ ei,
    const float* __restrict__ w1a, const float* __restrict__ b1a,
    const float* __restrict__ w1b, const float* __restrict__ b1b,
    const float* __restrict__ w2a, const float* __restrict__ b2a,
    const float* __restrict__ w2b, const float* __restrict__ b2b,
    const float* __restrict__ pw1, const float* __restrict__ pw2,
    const float* __restrict__ fc1w, const float* __restrict__ fc1b,
    const float* __restrict__ fc2w, const float* __restrict__ fc2b,
    const float* __restrict__ fc3w, const float* __restrict__ fc3b,
    const float* __restrict__ bn1g, const float* __restrict__ bn1b,
    const float* __restrict__ bn1m, const float* __restrict__ bn1v,
    const float* __restrict__ bn2g, const float* __restrict__ bn2b,
    const float* __restrict__ bn2m, const float* __restrict__ bn2v,
    float* __restrict__ out) {
  __shared__ __align__(16) float sY[6400];    // y1 (swz), later y2
  __shared__ __align__(16) float sAg[6400];   // w1a (unswz) during proj, then aggr
  __shared__ __align__(16) float sH[6400];    // conv outputs (swz)
  __shared__ __align__(16) float sHp[3200];   // pooled h (swz)
  __shared__ __align__(16) float sW[SW_SIZE];
  __shared__ __align__(16) int sSrc[7040];    // 4-aligned CSR src lists
  __shared__ unsigned short sEdge[6400];      // packed (src<<8)|dst
  __shared__ int sCnt[256], sStart[256], sOfs[256];
  __shared__ int sCnt2[256], sStart2[256], sOfs2[256];
  __shared__ int sFlag[4];
  __shared__ float sScore[256];
  __shared__ int sNewid[256];
  __shared__ float sZ[64];
  __shared__ float sZ1[128];
  __shared__ float sZ2[256];
  __shared__ float sLg[2];

  const int tid = threadIdx.x;
  const int g = blockIdx.x;

  // ================= A0: stage weights + pack edges + zero counters ========
  if (tid < 256) {
    for (int i = tid; i < 1600; i += 256)
      *(float4*)&sAg[i * 4] = ((const float4*)w1a)[i];
    if (tid < 32) {
      sW[B1A_OFF + tid] = b1a[tid];
      sW[B1B_OFF + tid] = b1b[tid];
      sW[B2A_OFF + tid] = b2a[tid];
      sW[B2B_OFF + tid] = b2b[tid];
      sW[PW1_OFF + tid] = pw1[tid];
      sW[PW2_OFF + tid] = pw2[tid];
    }
  } else if (tid < 512) {
    const int t = tid - 256;
    for (int i = t; i < 768; i += 256) {
      const float4 v = (i < 256) ? ((const float4*)w1b)[i]
                    : (i < 512) ? ((const float4*)w2a)[i - 256]
                                : ((const float4*)w2b)[i - 512];
      const int off = (i < 256) ? W1B_OFF + i * 4
                    : (i < 512) ? W2A_OFF + (i - 256) * 4
                                : W2B_OFF + (i - 512) * 4;
      *(float4*)&sW[off] = v;
    }
    for (int i = t; i < 256; i += 256) {
      sCnt[i] = 0; sOfs[i] = 0; sCnt2[i] = 0; sOfs2[i] = 0;
    }
    if (t < 4) sFlag[t] = 0;
  } else {
    const int eb = g * EPER, nb = g * NNODE;
    for (int i = tid - 512; i < EPER / 4; i += 512) {
      const int4 ss = *(const int4*)&ei[eb + i * 4];
      const int4 dd = *(const int4*)&ei[ETOT + eb + i * 4];
      sEdge[i * 4 + 0] = (unsigned short)(((ss.x - nb) << 8) | (dd.x - nb));
      sEdge[i * 4 + 1] = (unsigned short)(((ss.y - nb) << 8) | (dd.y - nb));
      sEdge[i * 4 + 2] = (unsigned short)(((ss.z - nb) << 8) | (dd.z - nb));
      sEdge[i * 4 + 3] = (unsigned short)(((ss.w - nb) << 8) | (dd.w - nb));
    }
  }
  __syncthreads();

  // ============ A1: proj (waves 0-3)  ||  CSR1 build spin-chain (256-1023) ==
  if (tid < 200) {
    // y1 = x_g @ w1a : 4 rows x 8 cols per thread, K=200 streamed from HBM.
    const int rg = tid >> 2, cg = tid & 3;
    const int n0 = rg * 4, d0 = cg * 8;
    float acc[4][8];
#pragma unroll
    for (int r = 0; r < 4; ++r)
#pragma unroll
      for (int c = 0; c < 8; ++c) acc[r][c] = 0.f;
    const float* xg = x + ((size_t)g * NNODE + n0) * FIN;
    for (int k = 0; k < FIN; k += 4) {
      float4 xv[4];
#pragma unroll
      for (int r = 0; r < 4; ++r)
        xv[r] = *(const float4*)&xg[r * FIN + k];
#pragma unroll
      for (int j = 0; j < 4; ++j) {
        const float4 wa = *(const float4*)&sAg[(k + j) * 32 + d0];
        const float4 wb = *(const float4*)&sAg[(k + j) * 32 + d0 + 4];
#pragma unroll
        for (int r = 0; r < 4; ++r) {
          const float xs = (j == 0) ? xv[r].x : (j == 1) ? xv[r].y
                                   : (j == 2) ? xv[r].z : xv[r].w;
          acc[r][0] += xs * wa.x; acc[r][1] += xs * wa.y;
          acc[r][2] += xs * wa.z; acc[r][3] += xs * wa.w;
          acc[r][4] += xs * wb.x; acc[r][5] += xs * wb.y;
          acc[r][6] += xs * wb.z; acc[r][7] += xs * wb.w;
        }
      }
    }
#pragma unroll
    for (int r = 0; r < 4; ++r) {
      float4 o0, o1;
      o0.x = acc[r][0]; o0.y = acc[r][1]; o0.z = acc[r][2]; o0.w = acc[r][3];
      o1.x = acc[r][4]; o1.y = acc[r][5]; o1.z = acc[r][6]; o1.w = acc[r][7];
      *(float4*)&sY[swz(n0 + r, cg * 2)] = o0;
      *(float4*)&sY[swz(n0 + r, cg * 2 + 1)] = o1;
    }
  } else if (tid == 200) {
    float s = 0.f;
    for (int k = 0; k < 32; ++k) s += sW[PW1_OFF + k] * sW[PW1_OFF + k];
    sW[NRM1_OFF] = sqrtf(s);
  } else if (tid == 201) {
    float s = 0.f;
    for (int k = 0; k < 32; ++k) s += sW[PW2_OFF + k] * sW[PW2_OFF + k];
    sW[NRM2_OFF] = sqrtf(s);
  } else if (tid >= 256) {
    const int t = tid - 256;
    for (int e = t; e < EPER; e += 768)
      atomicAdd(&sCnt[sEdge[e] & 255], 1);
    __threadfence_block();
    atomicAdd(&sFlag[0], 1);
    if (tid >= 960) {
      lds_spin(&sFlag[0], 768);
      __threadfence_block();
      scan_counts(sCnt, sStart, tid - 960);
      __threadfence_block();
      if (tid == 960) atomicExch(&sFlag[1], 1);
    }
    lds_spin(&sFlag[1], 1);
    __threadfence_block();
    for (int e = t; e < EPER; e += 768) {
      const unsigned short p = sEdge[e];
      sSrc[sStart[p & 255] + atomicAdd(&sOfs[p & 255], 1)] = p >> 8;
    }
  }
  __syncthreads();

  // ---- E: aggr1 ----
  aggregate<NNODE>(sY, sAg, sSrc, sStart, sCnt, tid);
  __syncthreads();

  // ---- F: h = relu(relu(y1+aggr1+b1a) @ w1b + b1b), score1 fused ----
  mm2r<200, true, true, true, true>(sY, sAg, &sW[B1A_OFF], &sW[W1B_OFF], sH,
                                    &sW[B1B_OFF], &sW[PW1_OFF], &sW[NRM1_OFF],
                                    sScore, tid);
  __syncthreads();

  // ---- H: rank1 (stable descending == lax.top_k) + attn1 + newid + hp1 ----
  if (tid < NNODE * 4) {
    const int n = tid >> 2, q = tid & 3;
    const float s = sScore[n];
    int r = 0;
    for (int m = q * 50; m < q * 50 + 50; ++m) {
      const float sm = sScore[m];
      r += (sm > s) || (sm == s && m < n);
    }
    r += __shfl_xor(r, 1);
    r += __shfl_xor(r, 2);
    if (q == 0) {
      sNewid[n] = (r < KP1) ? r : -1;
      if (r < KP1) out[2 * NGRAPH + g * KP1 + r] = 1.f / (1.f + expf(-s));
    }
    if (r < KP1) {
#pragma unroll
      for (int c = 0; c < 2; ++c) {
        const int ch = q * 2 + c;
        float4 v = *(const float4*)&sH[swz(n, ch)];
        v.x *= s; v.y *= s; v.z *= s; v.w *= s;
        *(float4*)&sHp[swz(r, ch)] = v;
      }
    }
  }
  __syncthreads();

  // ---- I: y2 = hp1 @ w2a (0-199) || x1 readout (256-287) || CSR2 (512+) ----
  mm2r<KP1, false, false, false, false>(sHp, nullptr, nullptr, &sW[W2A_OFF],
                                        sY, nullptr, nullptr, nullptr, nullptr,
                                        tid);
  if (tid >= 256 && tid < 288) {
    const int t = tid - 256;
    const int ch = t >> 2, w = t & 3;
    float m0 = -INFINITY, m1 = -INFINITY, s0 = 0.f, s1 = 0.f;
    for (int r = 0; r < KP1; r += 2) {
      const float v0 = sHp[swz(r, ch) + w];
      const float v1 = sHp[swz(r + 1, ch) + w];
      m0 = fmaxf(m0, v0); m1 = fmaxf(m1, v1);
      s0 += v0; s1 += v1;
    }
    sZ[t] = fmaxf(m0, m1);
    sZ[32 + t] = (s0 + s1) / (float)KP1;
  } else if (tid >= 512) {
    const int t = tid - 512;
    for (int e = t; e < EPER; e += 512) {
      const unsigned short p = sEdge[e];
      const int s1 = sNewid[p >> 8], d1 = sNewid[p & 255];
      if (s1 >= 0 && d1 >= 0) atomicAdd(&sCnt2[d1], 1);
    }
    __threadfence_block();
    atomicAdd(&sFlag[2], 1);
    if (tid >= 960) {
      lds_spin(&sFlag[2], 512);
      __threadfence_block();
      scan_counts(sCnt2, sStart2, tid - 960);
      __threadfence_block();
      if (tid == 960) atomicExch(&sFlag[3], 1);
    }
    lds_spin(&sFlag[3], 1);
    __threadfence_block();
    for (int e = t; e < EPER; e += 512) {
      const unsigned short p = sEdge[e];
      const int s1 = sNewid[p >> 8], d1 = sNewid[p & 255];
      if (s1 >= 0 && d1 >= 0)
        sSrc[sStart2[d1] + atomicAdd(&sOfs2[d1], 1)] = s1;
    }
  }
  __syncthreads();

  // ---- L: aggr2 ----
  aggregate<KP1>(sY, sAg, sSrc, sStart2, sCnt2, tid);
  __syncthreads();

  // ---- M: hc2 = relu(relu(y2+aggr2+b2a) @ w2b + b2b), score2 fused ----
  mm2r<KP1, true, true, true, true>(sY, sAg, &sW[B2A_OFF], &sW[W2B_OFF], sH,
                                    &sW[B2B_OFF], &sW[PW2_OFF], &sW[NRM2_OFF],
                                    sScore, tid);
  __syncthreads();

  // ---- N: rank2 + attn2 + hp2 ----
  if (tid < KP1 * 4) {
    const int n = tid >> 2, q = tid & 3;
    const float s = sScore[n];
    int r = 0;
    for (int m = q * 25; m < q * 25 + 25; ++m) {
      const float sm = sScore[m];
      r += (sm > s) || (sm == s && m < n);
    }
    r += __shfl_xor(r, 1);
    r += __shfl_xor(r, 2);
    if (q == 0) {
      sNewid[n] = (r < KP2) ? r : -1;
      if (r < KP2)
        out[2 * NGRAPH + NGRAPH * KP1 + g * KP2 + r] = 1.f / (1.f + expf(-s));
    }
    if (r < KP2) {
#pragma unroll
      for (int c = 0; c < 2; ++c) {
        const int ch = q * 2 + c;
        float4 v = *(const float4*)&sH[swz(n, ch)];
        v.x *= s; v.y *= s; v.z *= s; v.w *= s;
        *(float4*)&sHp[swz(r, ch)] = v;
      }
    }
  }
  __syncthreads();

  // ---- Q: x2 readout, z = x1 + x2 ----
  if (tid < 32) {
    const int ch = tid >> 2, w = tid & 3;
    float m0 = -INFINITY, m1 = -INFINITY, s0 = 0.f, s1 = 0.f;
    for (int r = 0; r < KP2; r += 2) {
      const float v0 = sHp[swz(r, ch) + w];
      const float v1 = sHp[swz(r + 1, ch) + w];
      m0 = fmaxf(m0, v0); m1 = fmaxf(m1, v1);
      s0 += v0; s1 += v1;
    }
    sZ[tid] += fmaxf(m0, m1);
    sZ[32 + tid] += (s0 + s1) / (float)KP2;
  }
  __syncthreads();

  // ---- R: fc1 + bn1 (512 threads, split-K 4-way) ----
  if (tid < 512) {
    const int o = tid >> 2, q = tid & 3;
    float a = 0.f;
    for (int k = q * 16; k < q * 16 + 16; ++k) a += sZ[k] * fc1w[k * 128 + o];
    a += __shfl_xor(a, 1);
    a += __shfl_xor(a, 2);
    if (q == 0) {
      a += fc1b[o];
      a = fmaxf(a, 0.f);
      a = (a - bn1m[o]) * rsqrtf(bn1v[o] + 1e-5f) * bn1g[o] + bn1b[o];
      sZ1[o] = a;
    }
  }
  __syncthreads();

  // ---- S: fc2 + bn2 (512 threads, split-K 2-way) ----
  if (tid < 512) {
    const int o = tid >> 1, h = tid & 1;
    float a = 0.f;
    for (int k = h * 64; k < h * 64 + 64; ++k) a += sZ1[k] * fc2w[k * 256 + o];
    a += __shfl_xor(a, 1);
    if (h == 0) {
      a += fc2b[o];
      a = fmaxf(a, 0.f);
      a = (a - bn2m[o]) * rsqrtf(bn2v[o] + 1e-5f) * bn2g[o] + bn2b[o];
      sZ2[o] = a;
    }
  }
  __syncthreads();

  // ---- T: fc3 + log-softmax (one wave, no extra barrier) ----
  if (tid < 64) {
    const int k4 = tid * 4;
    float a0 = 0.f, a1 = 0.f;
#pragma unroll
    for (int k = 0; k < 4; ++k) {
      const float z = sZ2[k4 + k];
      a0 += z * fc3w[(k4 + k) * 2 + 0];
      a1 += z * fc3w[(k4 + k) * 2 + 1];
    }
#pragma unroll
    for (int off = 32; off; off >>= 1) {
      a0 += __shfl_xor(a0, off);
      a1 += __shfl_xor(a1, off);
    }
    if (tid == 0) {
      const float l0 = a0 + fc3b[0], l1 = a1 + fc3b[1];
      const float m = fmaxf(l0, l1);
      const float lse = m + logf(expf(l0 - m) + expf(l1 - m));
      out[g * 2 + 0] = l0 - lse;
      out[g * 2 + 1] = l1 - lse;
    }
  }
}

extern "C" void kernel_launch(void* const* d_in, const int* in_sizes, int n_in,
                              void* d_out, int out_size, void* d_ws,
                              size_t ws_size, hipStream_t stream) {
  (void)in_sizes; (void)n_in; (void)out_size; (void)d_ws; (void)ws_size;
  gin_fused<<<NGRAPH, 1024, 0, stream>>>(
      (const float*)d_in[0], (const int*)d_in[1],
      (const float*)d_in[3], (const float*)d_in[4],
      (const float*)d_in[5], (const float*)d_in[6],
      (const float*)d_in[7], (const float*)d_in[8],
      (const float*)d_in[9], (const float*)d_in[10],
      (const float*)d_in[11], (const float*)d_in[12],
      (const float*)d_in[13], (const float*)d_in[14],
      (const float*)d_in[15], (const float*)d_in[16],
      (const float*)d_in[17], (const float*)d_in[18],
      (const float*)d_in[19], (const float*)d_in[20],
      (const float*)d_in[21], (const float*)d_in[22],
      (const float*)d_in[23], (const float*)d_in[24],
      (const float*)d_in[25], (const float*)d_in[26],
      (float*)d_out);
}